// Round 5
// baseline (840.328 us; speedup 1.0000x reference)
//
#include <hip/hip_runtime.h>
#include <cstdint>
#include <cstddef>

#define T_DIM 2048
#define D_DIM 2048
#define HI_N 4
#define DI_N 64
#define H_N 16
#define DH_N 128
#define TOPK_N 512
#define NEG_F (-1e9f)
#define FA_NEG (-1e30f)

typedef __attribute__((ext_vector_type(8))) short short8;
typedef __attribute__((ext_vector_type(4))) float f32x4;
typedef unsigned short ushort_t;

__device__ __forceinline__ unsigned short f2bf(float f) {
  unsigned u = __float_as_uint(f);
  u += 0x7FFFu + ((u >> 16) & 1u);   // RNE
  return (unsigned short)(u >> 16);
}
__device__ __forceinline__ float bf2f(unsigned short b) {
  return __uint_as_float((unsigned)b << 16);
}

// ---------------------------------------------------------------------------
// Fused indexer projections (fp32): qi[2048][256], ki[2048][64], wI[2048][4].
// ---------------------------------------------------------------------------
__global__ __launch_bounds__(256) void idx_proj(const float* __restrict__ x,
                                                const float* __restrict__ Wq_idx,
                                                const float* __restrict__ Wk_idx,
                                                const float* __restrict__ Ww_idx,
                                                float* __restrict__ qi,
                                                float* __restrict__ ki,
                                                float* __restrict__ wI) {
  __shared__ float As[2][16][64];
  __shared__ float Bs[2][16][64];
  const int bm = blockIdx.y << 6;
  const int bn_id = blockIdx.x;
  const float* B; float* C; int ldB, cb, ncols;
  if (bn_id < 4)       { B = Wq_idx; C = qi; ldB = 256; cb = bn_id << 6; ncols = 64; }
  else if (bn_id == 4) { B = Wk_idx; C = ki; ldB = 64;  cb = 0;          ncols = 64; }
  else                 { B = Ww_idx; C = wI; ldB = 4;   cb = 0;          ncols = 4;  }
  const int tid = threadIdx.x;
  const int tx = tid & 15, ty = tid >> 4;
  const int am = tid >> 2;          // 0..63
  const int ak = (tid & 3) << 2;    // 0,4,8,12
  float acc[4][4] = {};

  float4 a4 = *(const float4*)&x[(size_t)(bm + am) * 2048 + ak];
  float4 b4 = make_float4(0, 0, 0, 0);
  if ((tx << 2) < ncols) b4 = *(const float4*)&B[(size_t)ty * ldB + cb + (tx << 2)];
  As[0][ak + 0][am] = a4.x; As[0][ak + 1][am] = a4.y;
  As[0][ak + 2][am] = a4.z; As[0][ak + 3][am] = a4.w;
  *(float4*)&Bs[0][ty][tx << 2] = b4;

  int p = 0;
  for (int k0 = 0; k0 < 2048; k0 += 16) {
    __syncthreads();
    const bool more = (k0 + 16) < 2048;
    if (more) {
      a4 = *(const float4*)&x[(size_t)(bm + am) * 2048 + k0 + 16 + ak];
      if ((tx << 2) < ncols)
        b4 = *(const float4*)&B[(size_t)(k0 + 16 + ty) * ldB + cb + (tx << 2)];
    }
#pragma unroll
    for (int kk = 0; kk < 16; ++kk) {
      float4 av4 = *(const float4*)&As[p][kk][ty << 2];
      float4 bv4 = *(const float4*)&Bs[p][kk][tx << 2];
      float av[4] = {av4.x, av4.y, av4.z, av4.w};
      float bv[4] = {bv4.x, bv4.y, bv4.z, bv4.w};
#pragma unroll
      for (int i = 0; i < 4; ++i)
#pragma unroll
        for (int j = 0; j < 4; ++j) acc[i][j] += av[i] * bv[j];
    }
    if (more) {
      As[1 - p][ak + 0][am] = a4.x; As[1 - p][ak + 1][am] = a4.y;
      As[1 - p][ak + 2][am] = a4.z; As[1 - p][ak + 3][am] = a4.w;
      *(float4*)&Bs[1 - p][ty][tx << 2] = b4;
    }
    p ^= 1;
  }
#pragma unroll
  for (int i = 0; i < 4; ++i) {
    int m = bm + (ty << 2) + i;
    int n0 = tx << 2;
    if (n0 + 3 < ncols) {
      *(float4*)&C[(size_t)m * ldB + cb + n0] =
          make_float4(acc[i][0], acc[i][1], acc[i][2], acc[i][3]);
    } else {
#pragma unroll
      for (int j = 0; j < 4; ++j)
        if (n0 + j < ncols) C[(size_t)m * ldB + cb + n0 + j] = acc[i][j];
    }
  }
}

// ---------------------------------------------------------------------------
// casts / transposes
// ---------------------------------------------------------------------------
__global__ __launch_bounds__(256) void cast_bf16(const float* __restrict__ in,
                                                 ushort_t* __restrict__ out) {
  int i = (blockIdx.x * 256 + threadIdx.x) * 4;
  float4 f = *(const float4*)(in + i);
  ushort4 o;
  o.x = f2bf(f.x); o.y = f2bf(f.y); o.z = f2bf(f.z); o.w = f2bf(f.w);
  *(ushort4*)(out + i) = o;
}

// in[R][C] f32 -> out[C][R] bf16
__global__ __launch_bounds__(256) void cast_transpose(const float* __restrict__ in,
                                                      ushort_t* __restrict__ out,
                                                      int R, int C) {
  __shared__ float tile[32][33];
  const int bx = blockIdx.x * 32;
  const int by = blockIdx.y * 32;
  const int tx = threadIdx.x & 31, ty = threadIdx.x >> 5;
#pragma unroll
  for (int i = 0; i < 32; i += 8)
    tile[ty + i][tx] = in[(size_t)(by + ty + i) * C + bx + tx];
  __syncthreads();
#pragma unroll
  for (int i = 0; i < 32; i += 8)
    out[(size_t)(bx + ty + i) * R + by + tx] = f2bf(tile[tx][ty + i]);
}

// bf16 [T][ldin] -> [C][T]
__global__ __launch_bounds__(256) void transpose_bf(const ushort_t* __restrict__ in,
                                                    ushort_t* __restrict__ out,
                                                    int ldin) {
  __shared__ ushort_t tile[64][68];
  const int bx = blockIdx.x * 64;
  const int by = blockIdx.y * 64;
  const int tid = threadIdx.x;
#pragma unroll
  for (int p = 0; p < 4; ++p) {
    int r = p * 16 + (tid >> 4), c0 = (tid & 15) * 4;
    *(ushort4*)&tile[r][c0] = *(const ushort4*)(in + (size_t)(by + r) * ldin + bx + c0);
  }
  __syncthreads();
#pragma unroll
  for (int p = 0; p < 4; ++p) {
    int r = p * 16 + (tid >> 4), c0 = (tid & 15) * 4;
    ushort4 o;
    o.x = tile[c0 + 0][r]; o.y = tile[c0 + 1][r];
    o.z = tile[c0 + 2][r]; o.w = tile[c0 + 3][r];
    *(ushort4*)(out + (size_t)(bx + r) * T_DIM + by + c0) = o;
  }
}

// ---------------------------------------------------------------------------
// bf16 MFMA GEMM: C[M,N] = A[M,K] @ Bt[N,K]^T (m97 structure)
// ---------------------------------------------------------------------------
template <int OUT_BF16>
__global__ __launch_bounds__(256) void gemm_bt(const ushort_t* __restrict__ A,
                                               const ushort_t* __restrict__ Bt,
                                               void* __restrict__ C,
                                               int M, int N, int K) {
  __shared__ __attribute__((aligned(16))) ushort_t As[128 * 64];
  __shared__ __attribute__((aligned(16))) ushort_t Bs[128 * 64];
  const int bm = blockIdx.y << 7;
  const int bn = blockIdx.x << 7;
  const int tid = threadIdx.x;
  const int lane = tid & 63;
  const int wv = tid >> 6;
  const int wm = (wv >> 1) << 6;
  const int wn = (wv & 1) << 6;

  f32x4 acc[4][4] = {};

  const int sr = tid >> 3;
  const int sc = (tid & 7) << 3;
  const ushort_t* ga = A + (size_t)(bm + sr) * K + sc;
  const ushort_t* gb = Bt + (size_t)(bn + sr) * K + sc;
  const size_t rstep = (size_t)32 * K;

  for (int k0 = 0; k0 < K; k0 += 64) {
#pragma unroll
    for (int i = 0; i < 4; ++i) {
      __builtin_amdgcn_global_load_lds(
          (const __attribute__((address_space(1))) unsigned int*)(ga + i * rstep + k0),
          (__attribute__((address_space(3))) unsigned int*)(As + i * 2048 + tid * 8),
          16, 0, 0);
      __builtin_amdgcn_global_load_lds(
          (const __attribute__((address_space(1))) unsigned int*)(gb + i * rstep + k0),
          (__attribute__((address_space(3))) unsigned int*)(Bs + i * 2048 + tid * 8),
          16, 0, 0);
    }
    __syncthreads();
#pragma unroll
    for (int ks = 0; ks < 2; ++ks) {
      short8 af[4], bfr[4];
      const int kk = (ks << 5) + ((lane >> 4) << 3);
#pragma unroll
      for (int i = 0; i < 4; ++i) {
        af[i]  = *(const short8*)(As + (wm + (i << 4) + (lane & 15)) * 64 + kk);
        bfr[i] = *(const short8*)(Bs + (wn + (i << 4) + (lane & 15)) * 64 + kk);
      }
#pragma unroll
      for (int i = 0; i < 4; ++i)
#pragma unroll
        for (int j = 0; j < 4; ++j)
          acc[i][j] = __builtin_amdgcn_mfma_f32_16x16x32_bf16(af[i], bfr[j], acc[i][j], 0, 0, 0);
    }
    __syncthreads();
  }

  const int lrow = (lane >> 4) << 2;
  const int lcol = lane & 15;
#pragma unroll
  for (int i = 0; i < 4; ++i) {
    const int row = bm + wm + (i << 4) + lrow;
#pragma unroll
    for (int j = 0; j < 4; ++j) {
      const int col = bn + wn + (j << 4) + lcol;
#pragma unroll
      for (int r = 0; r < 4; ++r) {
        if (OUT_BF16)
          ((ushort_t*)C)[(size_t)(row + r) * N + col] = f2bf(acc[i][j][r]);
        else
          ((float*)C)[(size_t)(row + r) * N + col] = acc[i][j][r];
      }
    }
  }
}

// ---------------------------------------------------------------------------
// Lightning indexer scores (fp32 reg-tiled)
// ---------------------------------------------------------------------------
__global__ __launch_bounds__(256) void idx_scores_rt(const float* __restrict__ qi,
                                                     const float* __restrict__ ki,
                                                     const float* __restrict__ w,
                                                     float* __restrict__ out) {
  const int t0 = blockIdx.y << 6, s0 = blockIdx.x << 6;
  const int tid = threadIdx.x;
  const int tx = tid & 15, ty = tid >> 4;
  if (s0 > t0 + 63) {
    const float4 nf = make_float4(NEG_F, NEG_F, NEG_F, NEG_F);
#pragma unroll
    for (int i = 0; i < 4; ++i) {
      int m = t0 + (ty << 2) + i;
      *(float4*)&out[(size_t)m * T_DIM + s0 + (tx << 2)] = nf;
    }
    return;
  }
  __shared__ float As[16][64];
  __shared__ float Bs[16][64];
  __shared__ float wsh[64][4];
  if (tid < 64) *(float4*)wsh[tid] = *(const float4*)&w[(size_t)(t0 + tid) * 4];
  const int am = tid >> 2;
  const int ak = (tid & 3) << 2;
  float oacc[4][4] = {};
#pragma unroll
  for (int h = 0; h < HI_N; ++h) {
    float dacc[4][4] = {};
    for (int k0 = 0; k0 < DI_N; k0 += 16) {
      float4 qa = *(const float4*)&qi[(size_t)(t0 + am) * 256 + h * DI_N + k0 + ak];
      float4 kb = *(const float4*)&ki[(size_t)(s0 + am) * DI_N + k0 + ak];
      __syncthreads();
      As[ak + 0][am] = qa.x; As[ak + 1][am] = qa.y;
      As[ak + 2][am] = qa.z; As[ak + 3][am] = qa.w;
      Bs[ak + 0][am] = kb.x; Bs[ak + 1][am] = kb.y;
      Bs[ak + 2][am] = kb.z; Bs[ak + 3][am] = kb.w;
      __syncthreads();
#pragma unroll
      for (int kk = 0; kk < 16; ++kk) {
        float4 a4 = *(const float4*)&As[kk][ty << 2];
        float4 b4 = *(const float4*)&Bs[kk][tx << 2];
        float av[4] = {a4.x, a4.y, a4.z, a4.w};
        float bv[4] = {b4.x, b4.y, b4.z, b4.w};
#pragma unroll
        for (int i = 0; i < 4; ++i)
#pragma unroll
          for (int j = 0; j < 4; ++j) dacc[i][j] += av[i] * bv[j];
      }
    }
#pragma unroll
    for (int i = 0; i < 4; ++i) {
      float wh = wsh[(ty << 2) + i][h];
#pragma unroll
      for (int j = 0; j < 4; ++j) oacc[i][j] += fmaxf(dacc[i][j], 0.f) * wh;
    }
  }
#pragma unroll
  for (int i = 0; i < 4; ++i) {
    int m = t0 + (ty << 2) + i;
    int n0 = s0 + (tx << 2);
    float4 r;
    r.x = (n0 + 0 > m) ? NEG_F : oacc[i][0];
    r.y = (n0 + 1 > m) ? NEG_F : oacc[i][1];
    r.z = (n0 + 2 > m) ? NEG_F : oacc[i][2];
    r.w = (n0 + 3 > m) ? NEG_F : oacc[i][3];
    *(float4*)&out[(size_t)m * T_DIM + n0] = r;
  }
}

// ---------------------------------------------------------------------------
// Per-row top-512 -> bitmask (radix-histogram, jax tie semantics)
// ---------------------------------------------------------------------------
__global__ __launch_bounds__(256) void select_mask(const float* __restrict__ scores,
                                                   unsigned long long* __restrict__ maskbits) {
  const int t = blockIdx.x, tid = threadIdx.x;
  __shared__ unsigned int hist[256];
  __shared__ unsigned int s_prefix, s_krem;
  __shared__ unsigned char bytes[256];
  unsigned int uv[8];
  const float* row = scores + (size_t)t * T_DIM;
  {
    float4 f0 = *(const float4*)(row + tid * 8);
    float4 f1 = *(const float4*)(row + tid * 8 + 4);
    float fv[8] = {f0.x, f0.y, f0.z, f0.w, f1.x, f1.y, f1.z, f1.w};
#pragma unroll
    for (int j = 0; j < 8; ++j) {
      unsigned u = __float_as_uint(fv[j]);
      uv[j] = (u & 0x80000000u) ? ~u : (u | 0x80000000u);
    }
  }
  if (tid == 0) { s_prefix = 0u; s_krem = TOPK_N; }
  for (int p = 0; p < 4; ++p) {
    const int sh = 24 - 8 * p;
    hist[tid] = 0;
    __syncthreads();
    const unsigned pm = p ? (0xFFFFFFFFu << (32 - 8 * p)) : 0u;
    const unsigned prefix = s_prefix;
#pragma unroll
    for (int j = 0; j < 8; ++j)
      if ((uv[j] & pm) == prefix) atomicAdd(&hist[(uv[j] >> sh) & 255], 1u);
    __syncthreads();
    if (tid == 0) {
      unsigned krem = s_krem, cum = 0;
      int b = 255;
      for (;; --b) { cum += hist[b]; if (cum >= krem) break; }
      s_prefix = prefix | ((unsigned)b << sh);
      s_krem = krem - (cum - hist[b]);
    }
    __syncthreads();
  }
  const unsigned V = s_prefix;
  const int kr = (int)s_krem;
  int eqc = 0;
#pragma unroll
  for (int j = 0; j < 8; ++j) eqc += (uv[j] == V);
  __syncthreads();
  hist[tid] = (unsigned)eqc;
  __syncthreads();
  for (int off = 1; off < 256; off <<= 1) {
    int v = (int)hist[tid];
    if (tid >= off) v += (int)hist[tid - off];
    __syncthreads();
    hist[tid] = (unsigned)v;
    __syncthreads();
  }
  int run = (int)hist[tid] - eqc;
  unsigned char byte = 0;
#pragma unroll
  for (int j = 0; j < 8; ++j) {
    bool eq = (uv[j] == V);
    bool take = (uv[j] > V) || (eq && run < kr);
    run += eq;
    byte |= (unsigned char)(take ? (1u << j) : 0u);
  }
  bytes[tid] = byte;
  __syncthreads();
  if (tid < 32) {
    unsigned long long wqw = 0;
#pragma unroll
    for (int b = 0; b < 8; ++b)
      wqw |= (unsigned long long)bytes[tid * 8 + b] << (8 * b);
    maskbits[(size_t)t * 32 + tid] = wqw;
  }
}

// ---------------------------------------------------------------------------
// Flash masked attention v3 (bf16 MFMA). Block per (t-tile=128, head).
// XOR-swizzled LDS (conflict-free b128 under global_load_lds), P aliased into
// the K buffer (68 KB LDS -> 2 blocks/CU), direct O = P*V (no transpose).
// Swizzle: element (row,c) at row*128 + (((c>>3) ^ (row&15))<<3 | (c&7)).
// ---------------------------------------------------------------------------
__global__ __launch_bounds__(256, 2) void flash_attn3(
    const ushort_t* __restrict__ q, const ushort_t* __restrict__ k,
    const ushort_t* __restrict__ vt, const unsigned long long* __restrict__ maskbits,
    ushort_t* __restrict__ attn, int ldqk) {
  __shared__ __attribute__((aligned(16))) ushort_t Ks[128 * 128];   // Q stage -> K -> P (aliased)
  __shared__ __attribute__((aligned(16))) ushort_t Vts[128 * 128];  // Vt [d][s]
  __shared__ float mstate[2][128], lstate[2][128];
  __shared__ float pmax[2][128], psum[2][128];

  const int tt = blockIdx.x;
  const int h  = blockIdx.y;
  const int t0 = tt << 7;
  const int tid = threadIdx.x;
  const int lane = tid & 63;
  const int wv = tid >> 6;
  const int wm = (wv >> 1) << 6;
  const int wn = (wv & 1) << 6;
  const int l15 = lane & 15, l4 = lane >> 4;

  // staging geometry: lane handles dest (row = p*16 + (tid>>4), slot = tid&15);
  // swizzle => source chunk = slot ^ (tid>>4)  (row&15 == tid>>4 for all p)
  const int srow = tid >> 4;
  const int scol = ((tid & 15) ^ srow) << 3;

  // ---- prologue: stage Q (swizzled) -> Ks, extract fragments ----
  {
    const ushort_t* gq = q + (size_t)(t0 + srow) * ldqk + h * DH_N + scol;
#pragma unroll
    for (int p = 0; p < 8; ++p)
      __builtin_amdgcn_global_load_lds(
          (const __attribute__((address_space(1))) unsigned int*)(gq + (size_t)p * 16 * ldqk),
          (__attribute__((address_space(3))) unsigned int*)(Ks + p * 2048 + tid * 8), 16, 0, 0);
  }
  __syncthreads();
  short8 qfrag[4][4];
#pragma unroll
  for (int ks = 0; ks < 4; ++ks)
#pragma unroll
    for (int i = 0; i < 4; ++i)
      qfrag[ks][i] = *(const short8*)(Ks + (wm + i * 16 + l15) * 128 +
                                      (((ks * 4 + l4) ^ l15) << 3));
  if (tid < 128) { mstate[0][tid] = -INFINITY; lstate[0][tid] = 0.f; }

  f32x4 acc[4][4] = {};
  const int nst = (tt < 4) ? 4 : (tt + 1);
  const bool owner = ((wv & 1) == 0) && (l15 == 0);
  const float rsc = 0.08838834764831845f;  // 1/sqrt(128)

  for (int st = 0; st < nst; ++st) {
    const int s0 = st << 7;
    __syncthreads();  // all prev-iter LDS reads (P, Vt) and qfrag reads drained
    {
      const ushort_t* gk = k + (size_t)(s0 + srow) * ldqk + h * DH_N + scol;
      const ushort_t* gv = vt + (size_t)(h * DH_N + srow) * T_DIM + s0 + scol;
#pragma unroll
      for (int p = 0; p < 8; ++p) {
        __builtin_amdgcn_global_load_lds(
            (const __attribute__((address_space(1))) unsigned int*)(gk + (size_t)p * 16 * ldqk),
            (__attribute__((address_space(3))) unsigned int*)(Ks + p * 2048 + tid * 8), 16, 0, 0);
        __builtin_amdgcn_global_load_lds(
            (const __attribute__((address_space(1))) unsigned int*)(gv + (size_t)p * 16 * T_DIM),
            (__attribute__((address_space(3))) unsigned int*)(Vts + p * 2048 + tid * 8), 16, 0, 0);
      }
    }
    // mask words (overlap DMA latency)
    unsigned long long mw[4][4];
    {
      const int wbase = (s0 >> 6) + (wn >> 6);
#pragma unroll
      for (int i = 0; i < 4; ++i)
#pragma unroll
        for (int r = 0; r < 4; ++r)
          mw[i][r] = maskbits[(size_t)(t0 + wm + i * 16 + l4 * 4 + r) * 32 + wbase];
    }
    __syncthreads();  // K/Vt landed

    // ---- S = Q K^T (C-layout: row=t, col=s) ----
    f32x4 sacc[4][4] = {};
#pragma unroll
    for (int ks = 0; ks < 4; ++ks) {
      short8 bfr[4];
#pragma unroll
      for (int j = 0; j < 4; ++j)
        bfr[j] = *(const short8*)(Ks + (wn + j * 16 + l15) * 128 +
                                  (((ks * 4 + l4) ^ l15) << 3));
#pragma unroll
      for (int i = 0; i < 4; ++i)
#pragma unroll
        for (int j = 0; j < 4; ++j)
          sacc[i][j] = __builtin_amdgcn_mfma_f32_16x16x32_bf16(qfrag[ks][i], bfr[j], sacc[i][j], 0, 0, 0);
    }
    // scale + mask
#pragma unroll
    for (int i = 0; i < 4; ++i)
#pragma unroll
      for (int j = 0; j < 4; ++j)
#pragma unroll
        for (int r = 0; r < 4; ++r) {
          bool sel = (mw[i][r] >> (j * 16 + l15)) & 1;
          sacc[i][j][r] = sel ? sacc[i][j][r] * rsc : FA_NEG;
        }
    // row partial max -> LDS
    float pmx[4][4];
#pragma unroll
    for (int i = 0; i < 4; ++i)
#pragma unroll
      for (int r = 0; r < 4; ++r) {
        float m0 = fmaxf(fmaxf(sacc[i][0][r], sacc[i][1][r]), fmaxf(sacc[i][2][r], sacc[i][3][r]));
#pragma unroll
        for (int off = 1; off < 16; off <<= 1) m0 = fmaxf(m0, __shfl_xor(m0, off));
        pmx[i][r] = m0;
      }
    if (l15 == 0)
#pragma unroll
      for (int i = 0; i < 4; ++i)
#pragma unroll
        for (int r = 0; r < 4; ++r)
          pmax[wv & 1][wm + i * 16 + l4 * 4 + r] = pmx[i][r];
    __syncthreads();  // pmax visible; all K reads done -> Ks reusable as P

    const int rp = st & 1, wp = 1 - rp;
    float nmr[4][4], alpha_r[4][4];
#pragma unroll
    for (int i = 0; i < 4; ++i)
#pragma unroll
      for (int r = 0; r < 4; ++r) {
        int rw = wm + i * 16 + l4 * 4 + r;
        float mo = mstate[rp][rw];
        float nm = fmaxf(mo, fmaxf(pmax[0][rw], pmax[1][rw]));
        nmr[i][r] = nm;
        alpha_r[i][r] = __expf(mo - nm);
      }
    if (owner)
#pragma unroll
      for (int i = 0; i < 4; ++i)
#pragma unroll
        for (int r = 0; r < 4; ++r)
          mstate[wp][wm + i * 16 + l4 * 4 + r] = nmr[i][r];

    // P = exp(S-nm), row sums; write P into Ks (swizzled [t][s])
    float psr[4][4] = {};
#pragma unroll
    for (int i = 0; i < 4; ++i)
#pragma unroll
      for (int j = 0; j < 4; ++j)
#pragma unroll
        for (int r = 0; r < 4; ++r) {
          float s = sacc[i][j][r];
          float pv = (s <= -1e29f) ? 0.f : __expf(s - nmr[i][r]);
          sacc[i][j][r] = pv;
          psr[i][r] += pv;
        }
#pragma unroll
    for (int i = 0; i < 4; ++i)
#pragma unroll
      for (int j = 0; j < 4; ++j) {
        const int s = wn + j * 16 + l15;
        const int sc8 = s >> 3, s7 = s & 7;
#pragma unroll
        for (int r = 0; r < 4; ++r) {
          const int t = wm + i * 16 + l4 * 4 + r;
          Ks[t * 128 + (((sc8 ^ (t & 15)) << 3) | s7)] = f2bf(sacc[i][j][r]);
        }
      }
#pragma unroll
    for (int i = 0; i < 4; ++i)
#pragma unroll
      for (int r = 0; r < 4; ++r) {
        float sv = psr[i][r];
#pragma unroll
        for (int off = 1; off < 16; off <<= 1) sv += __shfl_xor(sv, off);
        psr[i][r] = sv;
      }
    if (l15 == 0)
#pragma unroll
      for (int i = 0; i < 4; ++i)
#pragma unroll
        for (int r = 0; r < 4; ++r)
          psum[wv & 1][wm + i * 16 + l4 * 4 + r] = psr[i][r];
    // rescale O accumulator per row
#pragma unroll
    for (int i = 0; i < 4; ++i)
#pragma unroll
      for (int j = 0; j < 4; ++j)
#pragma unroll
        for (int r = 0; r < 4; ++r)
          acc[i][j][r] *= alpha_r[i][r];
    __syncthreads();  // P + psum visible

    if (owner)
#pragma unroll
      for (int i = 0; i < 4; ++i)
#pragma unroll
        for (int r = 0; r < 4; ++r) {
          int rw = wm + i * 16 + l4 * 4 + r;
          lstate[wp][rw] = alpha_r[i][r] * lstate[rp][rw] + psum[0][rw] + psum[1][rw];
        }
    // ---- O += P V (af = P rows t, bfr = Vt rows d; C-layout row=t col=d) ----
#pragma unroll
    for (int ks = 0; ks < 4; ++ks) {
      short8 af[4], bfr[4];
#pragma unroll
      for (int i = 0; i < 4; ++i)
        af[i] = *(const short8*)(Ks + (wm + i * 16 + l15) * 128 +
                                 (((ks * 4 + l4) ^ l15) << 3));
#pragma unroll
      for (int j = 0; j < 4; ++j)
        bfr[j] = *(const short8*)(Vts + (wn + j * 16 + l15) * 128 +
                                  (((ks * 4 + l4) ^ l15) << 3));
#pragma unroll
      for (int i = 0; i < 4; ++i)
#pragma unroll
        for (int j = 0; j < 4; ++j)
          acc[i][j] = __builtin_amdgcn_mfma_f32_16x16x32_bf16(af[i], bfr[j], acc[i][j], 0, 0, 0);
    }
  }
  __syncthreads();  // lstate final visible
  const int fp = nst & 1;
  float linv[4][4];
#pragma unroll
  for (int i = 0; i < 4; ++i)
#pragma unroll
    for (int r = 0; r < 4; ++r)
      linv[i][r] = 1.f / lstate[fp][wm + i * 16 + l4 * 4 + r];
#pragma unroll
  for (int i = 0; i < 4; ++i)
#pragma unroll
    for (int j = 0; j < 4; ++j) {
      const int col = h * DH_N + wn + j * 16 + l15;
#pragma unroll
      for (int r = 0; r < 4; ++r) {
        const int row = t0 + wm + i * 16 + l4 * 4 + r;
        attn[(size_t)row * D_DIM + col] = f2bf(acc[i][j][r] * linv[i][r]);
      }
    }
}

// ---------------------------------------------------------------------------
extern "C" void kernel_launch(void* const* d_in, const int* in_sizes, int n_in,
                              void* d_out, int out_size, void* d_ws, size_t ws_size,
                              hipStream_t stream) {
  (void)in_sizes; (void)n_in; (void)out_size; (void)ws_size;
  const float* x      = (const float*)d_in[0];
  const float* Wq_idx = (const float*)d_in[1];
  const float* Wk_idx = (const float*)d_in[2];
  const float* Ww_idx = (const float*)d_in[3];
  const float* Wq     = (const float*)d_in[4];
  const float* Wk     = (const float*)d_in[5];
  const float* Wv     = (const float*)d_in[6];
  const float* Wo     = (const float*)d_in[7];
  float* out = (float*)d_out;

  char* ws = (char*)d_ws;
  const size_t MB = 1ull << 20;
  float*    scores  = (float*)(ws);
  ushort_t* qkv_bf  = (ushort_t*)(ws);
  unsigned long long* maskbits = (unsigned long long*)(ws + 25 * MB + 512 * 1024);
  ushort_t* x_bf    = (ushort_t*)(ws + 26 * MB);
  ushort_t* Wcat_t  = (ushort_t*)(ws + 34 * MB);
  ushort_t* vt_bf   = (ushort_t*)(ws + 34 * MB);
  ushort_t* attn_bf = (ushort_t*)(ws + 42 * MB);
  ushort_t* Wo_t    = (ushort_t*)(ws + 58 * MB);
  float*    qi      = (float*)(ws + 66 * MB);
  float*    ki      = (float*)(ws + 68 * MB);
  float*    wI      = (float*)(ws + 68 * MB + 512 * 1024);

  const dim3 blk(256);
  const dim3 tgrid(D_DIM / 32, D_DIM / 32);

  cast_bf16<<<dim3((D_DIM * T_DIM) / 1024), blk, 0, stream>>>(x, x_bf);
  cast_transpose<<<tgrid, blk, 0, stream>>>(Wq, Wcat_t, D_DIM, D_DIM);
  cast_transpose<<<tgrid, blk, 0, stream>>>(Wk, Wcat_t + (size_t)D_DIM * D_DIM, D_DIM, D_DIM);
  cast_transpose<<<tgrid, blk, 0, stream>>>(Wv, Wcat_t + (size_t)2 * D_DIM * D_DIM, D_DIM, D_DIM);
  cast_transpose<<<tgrid, blk, 0, stream>>>(Wo, Wo_t, D_DIM, D_DIM);

  // indexer path (fp32)
  idx_proj<<<dim3(6, T_DIM / 64), blk, 0, stream>>>(x, Wq_idx, Wk_idx, Ww_idx, qi, ki, wI);
  idx_scores_rt<<<dim3(T_DIM / 64, T_DIM / 64), blk, 0, stream>>>(qi, ki, wI, scores);
  select_mask<<<dim3(T_DIM), blk, 0, stream>>>(scores, maskbits);

  // fused qkv projection: [2048][6144] = x_bf @ Wcat_t^T (overwrites scores)
  gemm_bt<1><<<dim3(3 * D_DIM / 128, T_DIM / 128), blk, 0, stream>>>(
      x_bf, Wcat_t, qkv_bf, T_DIM, 3 * D_DIM, D_DIM);

  // v^T (vt overwrites Wq_t -- dead)
  transpose_bf<<<dim3(D_DIM / 64, T_DIM / 64), blk, 0, stream>>>(
      qkv_bf + 2 * D_DIM, vt_bf, 3 * D_DIM);

  // flash masked attention
  flash_attn3<<<dim3(T_DIM / 128, H_N), blk, 0, stream>>>(
      qkv_bf, qkv_bf + D_DIM, vt_bf, maskbits, attn_bf, 3 * D_DIM);

  // output projection -> f32
  gemm_bt<0><<<dim3(D_DIM / 128, T_DIM / 128), blk, 0, stream>>>(
      attn_bf, Wo_t, out, T_DIM, D_DIM, D_DIM);
}

// Round 6
// 600.333 us; speedup vs baseline: 1.3998x; 1.3998x over previous
//
#include <hip/hip_runtime.h>
#include <cstdint>
#include <cstddef>

#define T_DIM 2048
#define D_DIM 2048
#define HI_N 4
#define DI_N 64
#define H_N 16
#define DH_N 128
#define TOPK_N 512
#define NEG_F (-1e9f)
#define FA_NEG (-1e30f)

typedef __attribute__((ext_vector_type(8))) short short8;
typedef __attribute__((ext_vector_type(4))) float f32x4;
typedef unsigned short ushort_t;

__device__ __forceinline__ unsigned short f2bf(float f) {
  unsigned u = __float_as_uint(f);
  u += 0x7FFFu + ((u >> 16) & 1u);   // RNE
  return (unsigned short)(u >> 16);
}
__device__ __forceinline__ float bf2f(unsigned short b) {
  return __uint_as_float((unsigned)b << 16);
}

// ---------------------------------------------------------------------------
// Fused indexer projections (fp32): qi[2048][256], ki[2048][64], wI[2048][4].
// ---------------------------------------------------------------------------
__global__ __launch_bounds__(256) void idx_proj(const float* __restrict__ x,
                                                const float* __restrict__ Wq_idx,
                                                const float* __restrict__ Wk_idx,
                                                const float* __restrict__ Ww_idx,
                                                float* __restrict__ qi,
                                                float* __restrict__ ki,
                                                float* __restrict__ wI) {
  __shared__ float As[2][16][64];
  __shared__ float Bs[2][16][64];
  const int bm = blockIdx.y << 6;
  const int bn_id = blockIdx.x;
  const float* B; float* C; int ldB, cb, ncols;
  if (bn_id < 4)       { B = Wq_idx; C = qi; ldB = 256; cb = bn_id << 6; ncols = 64; }
  else if (bn_id == 4) { B = Wk_idx; C = ki; ldB = 64;  cb = 0;          ncols = 64; }
  else                 { B = Ww_idx; C = wI; ldB = 4;   cb = 0;          ncols = 4;  }
  const int tid = threadIdx.x;
  const int tx = tid & 15, ty = tid >> 4;
  const int am = tid >> 2;
  const int ak = (tid & 3) << 2;
  float acc[4][4] = {};

  float4 a4 = *(const float4*)&x[(size_t)(bm + am) * 2048 + ak];
  float4 b4 = make_float4(0, 0, 0, 0);
  if ((tx << 2) < ncols) b4 = *(const float4*)&B[(size_t)ty * ldB + cb + (tx << 2)];
  As[0][ak + 0][am] = a4.x; As[0][ak + 1][am] = a4.y;
  As[0][ak + 2][am] = a4.z; As[0][ak + 3][am] = a4.w;
  *(float4*)&Bs[0][ty][tx << 2] = b4;

  int p = 0;
  for (int k0 = 0; k0 < 2048; k0 += 16) {
    __syncthreads();
    const bool more = (k0 + 16) < 2048;
    if (more) {
      a4 = *(const float4*)&x[(size_t)(bm + am) * 2048 + k0 + 16 + ak];
      if ((tx << 2) < ncols)
        b4 = *(const float4*)&B[(size_t)(k0 + 16 + ty) * ldB + cb + (tx << 2)];
    }
#pragma unroll
    for (int kk = 0; kk < 16; ++kk) {
      float4 av4 = *(const float4*)&As[p][kk][ty << 2];
      float4 bv4 = *(const float4*)&Bs[p][kk][tx << 2];
      float av[4] = {av4.x, av4.y, av4.z, av4.w};
      float bv[4] = {bv4.x, bv4.y, bv4.z, bv4.w};
#pragma unroll
      for (int i = 0; i < 4; ++i)
#pragma unroll
        for (int j = 0; j < 4; ++j) acc[i][j] += av[i] * bv[j];
    }
    if (more) {
      As[1 - p][ak + 0][am] = a4.x; As[1 - p][ak + 1][am] = a4.y;
      As[1 - p][ak + 2][am] = a4.z; As[1 - p][ak + 3][am] = a4.w;
      *(float4*)&Bs[1 - p][ty][tx << 2] = b4;
    }
    p ^= 1;
  }
#pragma unroll
  for (int i = 0; i < 4; ++i) {
    int m = bm + (ty << 2) + i;
    int n0 = tx << 2;
    if (n0 + 3 < ncols) {
      *(float4*)&C[(size_t)m * ldB + cb + n0] =
          make_float4(acc[i][0], acc[i][1], acc[i][2], acc[i][3]);
    } else {
#pragma unroll
      for (int j = 0; j < 4; ++j)
        if (n0 + j < ncols) C[(size_t)m * ldB + cb + n0 + j] = acc[i][j];
    }
  }
}

// ---------------------------------------------------------------------------
// casts / transposes
// ---------------------------------------------------------------------------
__global__ __launch_bounds__(256) void cast_bf16(const float* __restrict__ in,
                                                 ushort_t* __restrict__ out) {
  int i = (blockIdx.x * 256 + threadIdx.x) * 4;
  float4 f = *(const float4*)(in + i);
  ushort4 o;
  o.x = f2bf(f.x); o.y = f2bf(f.y); o.z = f2bf(f.z); o.w = f2bf(f.w);
  *(ushort4*)(out + i) = o;
}

// in[R][C] f32 -> out[C][R] bf16
__global__ __launch_bounds__(256) void cast_transpose(const float* __restrict__ in,
                                                      ushort_t* __restrict__ out,
                                                      int R, int C) {
  __shared__ float tile[32][33];
  const int bx = blockIdx.x * 32;
  const int by = blockIdx.y * 32;
  const int tx = threadIdx.x & 31, ty = threadIdx.x >> 5;
#pragma unroll
  for (int i = 0; i < 32; i += 8)
    tile[ty + i][tx] = in[(size_t)(by + ty + i) * C + bx + tx];
  __syncthreads();
#pragma unroll
  for (int i = 0; i < 32; i += 8)
    out[(size_t)(bx + ty + i) * R + by + tx] = f2bf(tile[tx][ty + i]);
}

// bf16 [T][ldin] -> [C][T]
__global__ __launch_bounds__(256) void transpose_bf(const ushort_t* __restrict__ in,
                                                    ushort_t* __restrict__ out,
                                                    int ldin) {
  __shared__ ushort_t tile[64][68];
  const int bx = blockIdx.x * 64;
  const int by = blockIdx.y * 64;
  const int tid = threadIdx.x;
#pragma unroll
  for (int p = 0; p < 4; ++p) {
    int r = p * 16 + (tid >> 4), c0 = (tid & 15) * 4;
    *(ushort4*)&tile[r][c0] = *(const ushort4*)(in + (size_t)(by + r) * ldin + bx + c0);
  }
  __syncthreads();
#pragma unroll
  for (int p = 0; p < 4; ++p) {
    int r = p * 16 + (tid >> 4), c0 = (tid & 15) * 4;
    ushort4 o;
    o.x = tile[c0 + 0][r]; o.y = tile[c0 + 1][r];
    o.z = tile[c0 + 2][r]; o.w = tile[c0 + 3][r];
    *(ushort4*)(out + (size_t)(bx + r) * T_DIM + by + c0) = o;
  }
}

// qkv [T][6144] -> q_h [16][T][128], k_h [16][T][128] (head-major copies)
__global__ __launch_bounds__(256) void qk_head(const ushort_t* __restrict__ qkv,
                                               ushort_t* __restrict__ q_h,
                                               ushort_t* __restrict__ k_h) {
  const int h = blockIdx.x;
  const int s0 = blockIdx.y << 7;
  const int tid = threadIdx.x;
#pragma unroll
  for (int p = 0; p < 8; ++p) {
    const int r = p * 16 + (tid >> 4);
    const int c = (tid & 15) * 8;
    const size_t src = (size_t)(s0 + r) * (3 * D_DIM) + h * DH_N + c;
    const size_t dst = ((size_t)h * T_DIM + s0 + r) * DH_N + c;
    *(uint4*)(q_h + dst) = *(const uint4*)(qkv + src);
    *(uint4*)(k_h + dst) = *(const uint4*)(qkv + D_DIM + src);
  }
}

// ---------------------------------------------------------------------------
// bf16 MFMA GEMM: C[M,N] = A[M,K] @ Bt[N,K]^T (m97 structure)
// ---------------------------------------------------------------------------
template <int OUT_BF16>
__global__ __launch_bounds__(256) void gemm_bt(const ushort_t* __restrict__ A,
                                               const ushort_t* __restrict__ Bt,
                                               void* __restrict__ C,
                                               int M, int N, int K) {
  __shared__ __attribute__((aligned(16))) ushort_t As[128 * 64];
  __shared__ __attribute__((aligned(16))) ushort_t Bs[128 * 64];
  const int bm = blockIdx.y << 7;
  const int bn = blockIdx.x << 7;
  const int tid = threadIdx.x;
  const int lane = tid & 63;
  const int wv = tid >> 6;
  const int wm = (wv >> 1) << 6;
  const int wn = (wv & 1) << 6;

  f32x4 acc[4][4] = {};

  const int sr = tid >> 3;
  const int sc = (tid & 7) << 3;
  const ushort_t* ga = A + (size_t)(bm + sr) * K + sc;
  const ushort_t* gb = Bt + (size_t)(bn + sr) * K + sc;
  const size_t rstep = (size_t)32 * K;

  for (int k0 = 0; k0 < K; k0 += 64) {
#pragma unroll
    for (int i = 0; i < 4; ++i) {
      __builtin_amdgcn_global_load_lds(
          (const __attribute__((address_space(1))) unsigned int*)(ga + i * rstep + k0),
          (__attribute__((address_space(3))) unsigned int*)(As + i * 2048 + tid * 8),
          16, 0, 0);
      __builtin_amdgcn_global_load_lds(
          (const __attribute__((address_space(1))) unsigned int*)(gb + i * rstep + k0),
          (__attribute__((address_space(3))) unsigned int*)(Bs + i * 2048 + tid * 8),
          16, 0, 0);
    }
    __syncthreads();
#pragma unroll
    for (int ks = 0; ks < 2; ++ks) {
      short8 af[4], bfr[4];
      const int kk = (ks << 5) + ((lane >> 4) << 3);
#pragma unroll
      for (int i = 0; i < 4; ++i) {
        af[i]  = *(const short8*)(As + (wm + (i << 4) + (lane & 15)) * 64 + kk);
        bfr[i] = *(const short8*)(Bs + (wn + (i << 4) + (lane & 15)) * 64 + kk);
      }
#pragma unroll
      for (int i = 0; i < 4; ++i)
#pragma unroll
        for (int j = 0; j < 4; ++j)
          acc[i][j] = __builtin_amdgcn_mfma_f32_16x16x32_bf16(af[i], bfr[j], acc[i][j], 0, 0, 0);
    }
    __syncthreads();
  }

  const int lrow = (lane >> 4) << 2;
  const int lcol = lane & 15;
#pragma unroll
  for (int i = 0; i < 4; ++i) {
    const int row = bm + wm + (i << 4) + lrow;
#pragma unroll
    for (int j = 0; j < 4; ++j) {
      const int col = bn + wn + (j << 4) + lcol;
#pragma unroll
      for (int r = 0; r < 4; ++r) {
        if (OUT_BF16)
          ((ushort_t*)C)[(size_t)(row + r) * N + col] = f2bf(acc[i][j][r]);
        else
          ((float*)C)[(size_t)(row + r) * N + col] = acc[i][j][r];
      }
    }
  }
}

// ---------------------------------------------------------------------------
// Lightning indexer scores (fp32 reg-tiled)
// ---------------------------------------------------------------------------
__global__ __launch_bounds__(256) void idx_scores_rt(const float* __restrict__ qi,
                                                     const float* __restrict__ ki,
                                                     const float* __restrict__ w,
                                                     float* __restrict__ out) {
  const int t0 = blockIdx.y << 6, s0 = blockIdx.x << 6;
  const int tid = threadIdx.x;
  const int tx = tid & 15, ty = tid >> 4;
  if (s0 > t0 + 63) {
    const float4 nf = make_float4(NEG_F, NEG_F, NEG_F, NEG_F);
#pragma unroll
    for (int i = 0; i < 4; ++i) {
      int m = t0 + (ty << 2) + i;
      *(float4*)&out[(size_t)m * T_DIM + s0 + (tx << 2)] = nf;
    }
    return;
  }
  __shared__ float As[16][64];
  __shared__ float Bs[16][64];
  __shared__ float wsh[64][4];
  if (tid < 64) *(float4*)wsh[tid] = *(const float4*)&w[(size_t)(t0 + tid) * 4];
  const int am = tid >> 2;
  const int ak = (tid & 3) << 2;
  float oacc[4][4] = {};
#pragma unroll
  for (int h = 0; h < HI_N; ++h) {
    float dacc[4][4] = {};
    for (int k0 = 0; k0 < DI_N; k0 += 16) {
      float4 qa = *(const float4*)&qi[(size_t)(t0 + am) * 256 + h * DI_N + k0 + ak];
      float4 kb = *(const float4*)&ki[(size_t)(s0 + am) * DI_N + k0 + ak];
      __syncthreads();
      As[ak + 0][am] = qa.x; As[ak + 1][am] = qa.y;
      As[ak + 2][am] = qa.z; As[ak + 3][am] = qa.w;
      Bs[ak + 0][am] = kb.x; Bs[ak + 1][am] = kb.y;
      Bs[ak + 2][am] = kb.z; Bs[ak + 3][am] = kb.w;
      __syncthreads();
#pragma unroll
      for (int kk = 0; kk < 16; ++kk) {
        float4 a4 = *(const float4*)&As[kk][ty << 2];
        float4 b4 = *(const float4*)&Bs[kk][tx << 2];
        float av[4] = {a4.x, a4.y, a4.z, a4.w};
        float bv[4] = {b4.x, b4.y, b4.z, b4.w};
#pragma unroll
        for (int i = 0; i < 4; ++i)
#pragma unroll
          for (int j = 0; j < 4; ++j) dacc[i][j] += av[i] * bv[j];
      }
    }
#pragma unroll
    for (int i = 0; i < 4; ++i) {
      float wh = wsh[(ty << 2) + i][h];
#pragma unroll
      for (int j = 0; j < 4; ++j) oacc[i][j] += fmaxf(dacc[i][j], 0.f) * wh;
    }
  }
#pragma unroll
  for (int i = 0; i < 4; ++i) {
    int m = t0 + (ty << 2) + i;
    int n0 = s0 + (tx << 2);
    float4 r;
    r.x = (n0 + 0 > m) ? NEG_F : oacc[i][0];
    r.y = (n0 + 1 > m) ? NEG_F : oacc[i][1];
    r.z = (n0 + 2 > m) ? NEG_F : oacc[i][2];
    r.w = (n0 + 3 > m) ? NEG_F : oacc[i][3];
    *(float4*)&out[(size_t)m * T_DIM + n0] = r;
  }
}

// ---------------------------------------------------------------------------
// Per-row top-512 -> bitmask (radix-histogram, jax tie semantics)
// ---------------------------------------------------------------------------
__global__ __launch_bounds__(256) void select_mask(const float* __restrict__ scores,
                                                   unsigned long long* __restrict__ maskbits) {
  const int t = blockIdx.x, tid = threadIdx.x;
  __shared__ unsigned int hist[256];
  __shared__ unsigned int s_prefix, s_krem;
  __shared__ unsigned char bytes[256];
  unsigned int uv[8];
  const float* row = scores + (size_t)t * T_DIM;
  {
    float4 f0 = *(const float4*)(row + tid * 8);
    float4 f1 = *(const float4*)(row + tid * 8 + 4);
    float fv[8] = {f0.x, f0.y, f0.z, f0.w, f1.x, f1.y, f1.z, f1.w};
#pragma unroll
    for (int j = 0; j < 8; ++j) {
      unsigned u = __float_as_uint(fv[j]);
      uv[j] = (u & 0x80000000u) ? ~u : (u | 0x80000000u);
    }
  }
  if (tid == 0) { s_prefix = 0u; s_krem = TOPK_N; }
  for (int p = 0; p < 4; ++p) {
    const int sh = 24 - 8 * p;
    hist[tid] = 0;
    __syncthreads();
    const unsigned pm = p ? (0xFFFFFFFFu << (32 - 8 * p)) : 0u;
    const unsigned prefix = s_prefix;
#pragma unroll
    for (int j = 0; j < 8; ++j)
      if ((uv[j] & pm) == prefix) atomicAdd(&hist[(uv[j] >> sh) & 255], 1u);
    __syncthreads();
    if (tid == 0) {
      unsigned krem = s_krem, cum = 0;
      int b = 255;
      for (;; --b) { cum += hist[b]; if (cum >= krem) break; }
      s_prefix = prefix | ((unsigned)b << sh);
      s_krem = krem - (cum - hist[b]);
    }
    __syncthreads();
  }
  const unsigned V = s_prefix;
  const int kr = (int)s_krem;
  int eqc = 0;
#pragma unroll
  for (int j = 0; j < 8; ++j) eqc += (uv[j] == V);
  __syncthreads();
  hist[tid] = (unsigned)eqc;
  __syncthreads();
  for (int off = 1; off < 256; off <<= 1) {
    int v = (int)hist[tid];
    if (tid >= off) v += (int)hist[tid - off];
    __syncthreads();
    hist[tid] = (unsigned)v;
    __syncthreads();
  }
  int run = (int)hist[tid] - eqc;
  unsigned char byte = 0;
#pragma unroll
  for (int j = 0; j < 8; ++j) {
    bool eq = (uv[j] == V);
    bool take = (uv[j] > V) || (eq && run < kr);
    run += eq;
    byte |= (unsigned char)(take ? (1u << j) : 0u);
  }
  bytes[tid] = byte;
  __syncthreads();
  if (tid < 32) {
    unsigned long long wqw = 0;
#pragma unroll
    for (int b = 0; b < 8; ++b)
      wqw |= (unsigned long long)bytes[tid * 8 + b] << (8 * b);
    maskbits[(size_t)t * 32 + tid] = wqw;
  }
}

// ---------------------------------------------------------------------------
// Flash masked attention v4 (bf16 MFMA). Block per (head, t-tile=128).
// Head-major streaming inputs (q_h/k_h [h][T][128], vt [h*128+d][T]),
// lane-sequential DMA (coalesced), direct O = P*V, LDS-staged epilogue.
// blockIdx.x = h (fast): same-h blocks share K/V tiles on one XCD.
// ---------------------------------------------------------------------------
__global__ __launch_bounds__(256, 1) void flash_attn4(
    const ushort_t* __restrict__ q_h, const ushort_t* __restrict__ k_h,
    const ushort_t* __restrict__ vt, const unsigned long long* __restrict__ maskbits,
    ushort_t* __restrict__ attn) {
  __shared__ __attribute__((aligned(16))) ushort_t Ks[128 * 128];   // Q stage, then K [s][d]
  __shared__ __attribute__((aligned(16))) ushort_t Vts[128 * 128];  // Vt [d][s]
  __shared__ __attribute__((aligned(16))) ushort_t Ps[128 * 136];   // P [t][s] pad; O stage
  __shared__ float mstate[2][128], lstate[2][128];
  __shared__ float pmax[2][128], psum[2][128];

  const int h  = blockIdx.x;
  const int tt = blockIdx.y;
  const int t0 = tt << 7;
  const int tid = threadIdx.x;
  const int lane = tid & 63;
  const int wv = tid >> 6;
  const int wm = (wv >> 1) << 6;
  const int wn = (wv & 1) << 6;
  const int l15 = lane & 15, l4 = lane >> 4;

  const int srow = tid >> 4;           // 0..15
  const int scol = (tid & 15) << 3;    // element offset, lane-sequential

  // ---- prologue: stage Q -> Ks, extract fragments ----
  {
    const ushort_t* gq = q_h + ((size_t)h * T_DIM + t0 + srow) * DH_N + scol;
#pragma unroll
    for (int p = 0; p < 8; ++p)
      __builtin_amdgcn_global_load_lds(
          (const __attribute__((address_space(1))) unsigned int*)(gq + (size_t)p * 16 * DH_N),
          (__attribute__((address_space(3))) unsigned int*)(Ks + p * 2048 + tid * 8), 16, 0, 0);
  }
  __syncthreads();
  short8 qfrag[4][4];
#pragma unroll
  for (int ks = 0; ks < 4; ++ks)
#pragma unroll
    for (int i = 0; i < 4; ++i)
      qfrag[ks][i] = *(const short8*)(Ks + (wm + i * 16 + l15) * 128 + ks * 32 + l4 * 8);
  if (tid < 128) { mstate[0][tid] = -INFINITY; lstate[0][tid] = 0.f; }

  f32x4 acc[4][4] = {};
  const int nst = (tt < 4) ? 4 : (tt + 1);
  const bool owner = ((wv & 1) == 0) && (l15 == 0);
  const float rsc = 0.08838834764831845f;  // 1/sqrt(128)

  for (int st = 0; st < nst; ++st) {
    const int s0 = st << 7;
    __syncthreads();  // prev-iter Ks/Vts/Ps reads drained
    {
      const ushort_t* gk = k_h + ((size_t)h * T_DIM + s0 + srow) * DH_N + scol;
      const ushort_t* gv = vt + (size_t)(h * DH_N + srow) * T_DIM + s0 + scol;
#pragma unroll
      for (int p = 0; p < 8; ++p) {
        __builtin_amdgcn_global_load_lds(
            (const __attribute__((address_space(1))) unsigned int*)(gk + (size_t)p * 16 * DH_N),
            (__attribute__((address_space(3))) unsigned int*)(Ks + p * 2048 + tid * 8), 16, 0, 0);
        __builtin_amdgcn_global_load_lds(
            (const __attribute__((address_space(1))) unsigned int*)(gv + (size_t)p * 16 * T_DIM),
            (__attribute__((address_space(3))) unsigned int*)(Vts + p * 2048 + tid * 8), 16, 0, 0);
      }
    }
    // mask words (overlap DMA latency)
    unsigned long long mw[4][4];
    {
      const int wbase = (s0 >> 6) + (wn >> 6);
#pragma unroll
      for (int i = 0; i < 4; ++i)
#pragma unroll
        for (int r = 0; r < 4; ++r)
          mw[i][r] = maskbits[(size_t)(t0 + wm + i * 16 + l4 * 4 + r) * 32 + wbase];
    }
    __syncthreads();  // K/Vt landed

    // ---- S = Q K^T (row=t, col=s) ----
    f32x4 sacc[4][4] = {};
#pragma unroll
    for (int ks = 0; ks < 4; ++ks) {
      short8 bfr[4];
#pragma unroll
      for (int j = 0; j < 4; ++j)
        bfr[j] = *(const short8*)(Ks + (wn + j * 16 + l15) * 128 + ks * 32 + l4 * 8);
#pragma unroll
      for (int i = 0; i < 4; ++i)
#pragma unroll
        for (int j = 0; j < 4; ++j)
          sacc[i][j] = __builtin_amdgcn_mfma_f32_16x16x32_bf16(qfrag[ks][i], bfr[j], sacc[i][j], 0, 0, 0);
    }
    // scale + mask
#pragma unroll
    for (int i = 0; i < 4; ++i)
#pragma unroll
      for (int j = 0; j < 4; ++j)
#pragma unroll
        for (int r = 0; r < 4; ++r) {
          bool sel = (mw[i][r] >> (j * 16 + l15)) & 1;
          sacc[i][j][r] = sel ? sacc[i][j][r] * rsc : FA_NEG;
        }
    // row partial max -> LDS
    float pmx[4][4];
#pragma unroll
    for (int i = 0; i < 4; ++i)
#pragma unroll
      for (int r = 0; r < 4; ++r) {
        float m0 = fmaxf(fmaxf(sacc[i][0][r], sacc[i][1][r]), fmaxf(sacc[i][2][r], sacc[i][3][r]));
#pragma unroll
        for (int off = 1; off < 16; off <<= 1) m0 = fmaxf(m0, __shfl_xor(m0, off));
        pmx[i][r] = m0;
      }
    if (l15 == 0)
#pragma unroll
      for (int i = 0; i < 4; ++i)
#pragma unroll
        for (int r = 0; r < 4; ++r)
          pmax[wv & 1][wm + i * 16 + l4 * 4 + r] = pmx[i][r];
    __syncthreads();  // pmax visible

    const int rp = st & 1, wp = 1 - rp;
    float nmr[4][4], alpha_r[4][4];
#pragma unroll
    for (int i = 0; i < 4; ++i)
#pragma unroll
      for (int r = 0; r < 4; ++r) {
        int rw = wm + i * 16 + l4 * 4 + r;
        float mo = mstate[rp][rw];
        float nm = fmaxf(mo, fmaxf(pmax[0][rw], pmax[1][rw]));
        nmr[i][r] = nm;
        alpha_r[i][r] = __expf(mo - nm);
      }
    if (owner)
#pragma unroll
      for (int i = 0; i < 4; ++i)
#pragma unroll
        for (int r = 0; r < 4; ++r)
          mstate[wp][wm + i * 16 + l4 * 4 + r] = nmr[i][r];

    // P = exp(S-nm), row sums, write P -> Ps [t][s] (padded)
    float psr[4][4] = {};
#pragma unroll
    for (int i = 0; i < 4; ++i)
#pragma unroll
      for (int j = 0; j < 4; ++j)
#pragma unroll
        for (int r = 0; r < 4; ++r) {
          float s = sacc[i][j][r];
          float pv = (s <= -1e29f) ? 0.f : __expf(s - nmr[i][r]);
          sacc[i][j][r] = pv;
          psr[i][r] += pv;
        }
#pragma unroll
    for (int i = 0; i < 4; ++i)
#pragma unroll
      for (int j = 0; j < 4; ++j) {
        const int s = wn + j * 16 + l15;
#pragma unroll
        for (int r = 0; r < 4; ++r)
          Ps[(wm + i * 16 + l4 * 4 + r) * 136 + s] = f2bf(sacc[i][j][r]);
      }
#pragma unroll
    for (int i = 0; i < 4; ++i)
#pragma unroll
      for (int r = 0; r < 4; ++r) {
        float sv = psr[i][r];
#pragma unroll
        for (int off = 1; off < 16; off <<= 1) sv += __shfl_xor(sv, off);
        psr[i][r] = sv;
      }
    if (l15 == 0)
#pragma unroll
      for (int i = 0; i < 4; ++i)
#pragma unroll
        for (int r = 0; r < 4; ++r)
          psum[wv & 1][wm + i * 16 + l4 * 4 + r] = psr[i][r];
    // rescale O accumulator per row
#pragma unroll
    for (int i = 0; i < 4; ++i)
#pragma unroll
      for (int j = 0; j < 4; ++j)
#pragma unroll
        for (int r = 0; r < 4; ++r)
          acc[i][j][r] *= alpha_r[i][r];
    __syncthreads();  // P + psum visible

    if (owner)
#pragma unroll
      for (int i = 0; i < 4; ++i)
#pragma unroll
        for (int r = 0; r < 4; ++r) {
          int rw = wm + i * 16 + l4 * 4 + r;
          lstate[wp][rw] = alpha_r[i][r] * lstate[rp][rw] + psum[0][rw] + psum[1][rw];
        }
    // ---- O += P V (af = P rows t, bfr = Vt rows d) ----
#pragma unroll
    for (int ks = 0; ks < 4; ++ks) {
      short8 af[4], bfr[4];
#pragma unroll
      for (int i = 0; i < 4; ++i)
        af[i] = *(const short8*)(Ps + (wm + i * 16 + l15) * 136 + ks * 32 + l4 * 8);
#pragma unroll
      for (int j = 0; j < 4; ++j)
        bfr[j] = *(const short8*)(Vts + (wn + j * 16 + l15) * 128 + ks * 32 + l4 * 8);
#pragma unroll
      for (int i = 0; i < 4; ++i)
#pragma unroll
        for (int j = 0; j < 4; ++j)
          acc[i][j] = __builtin_amdgcn_mfma_f32_16x16x32_bf16(af[i], bfr[j], acc[i][j], 0, 0, 0);
    }
  }
  __syncthreads();  // lstate final visible
  const int fp = nst & 1;
  float linv[4][4];
#pragma unroll
  for (int i = 0; i < 4; ++i)
#pragma unroll
    for (int r = 0; r < 4; ++r)
      linv[i][r] = 1.f / lstate[fp][wm + i * 16 + l4 * 4 + r];
  // stage O (row=t, col=d) into Ps, then coalesced 16B stores
#pragma unroll
  for (int i = 0; i < 4; ++i)
#pragma unroll
    for (int j = 0; j < 4; ++j) {
      const int col = wn + j * 16 + l15;
#pragma unroll
      for (int r = 0; r < 4; ++r) {
        const int row = wm + i * 16 + l4 * 4 + r;
        Ps[row * 136 + col] = f2bf(acc[i][j][r] * linv[i][r]);
      }
    }
  __syncthreads();
#pragma unroll
  for (int p = 0; p < 8; ++p) {
    const int rw = p * 16 + (tid >> 4);
    const int d0 = (tid & 15) * 8;
    *(ulonglong2*)(attn + (size_t)(t0 + rw) * D_DIM + h * DH_N + d0) =
        *(const ulonglong2*)(Ps + rw * 136 + d0);
  }
}

// ---------------------------------------------------------------------------
extern "C" void kernel_launch(void* const* d_in, const int* in_sizes, int n_in,
                              void* d_out, int out_size, void* d_ws, size_t ws_size,
                              hipStream_t stream) {
  (void)in_sizes; (void)n_in; (void)out_size; (void)ws_size;
  const float* x      = (const float*)d_in[0];
  const float* Wq_idx = (const float*)d_in[1];
  const float* Wk_idx = (const float*)d_in[2];
  const float* Ww_idx = (const float*)d_in[3];
  const float* Wq     = (const float*)d_in[4];
  const float* Wk     = (const float*)d_in[5];
  const float* Wv     = (const float*)d_in[6];
  const float* Wo     = (const float*)d_in[7];
  float* out = (float*)d_out;

  char* ws = (char*)d_ws;
  const size_t MB = 1ull << 20;
  // layout (peak ~68.6 MB):
  //   [0,24)     scores f32 [0,16) -> qkv_bf [0,24) after select_mask
  //   [25.5,26)  maskbits
  //   [26,34)    x_bf -> k_h after qkv GEMM
  //   [34,58)    Wcat_t -> vt [34,42) + attn_bf [42,50) + q_h [50,58)
  //   [58,66)    Wo_t
  //   [66,68)    qi ; [68,68.5) ki ; +32K wI
  float*    scores  = (float*)(ws);
  ushort_t* qkv_bf  = (ushort_t*)(ws);
  unsigned long long* maskbits = (unsigned long long*)(ws + 25 * MB + 512 * 1024);
  ushort_t* x_bf    = (ushort_t*)(ws + 26 * MB);
  ushort_t* k_h     = (ushort_t*)(ws + 26 * MB);
  ushort_t* Wcat_t  = (ushort_t*)(ws + 34 * MB);
  ushort_t* vt_bf   = (ushort_t*)(ws + 34 * MB);
  ushort_t* attn_bf = (ushort_t*)(ws + 42 * MB);
  ushort_t* q_h     = (ushort_t*)(ws + 50 * MB);
  ushort_t* Wo_t    = (ushort_t*)(ws + 58 * MB);
  float*    qi      = (float*)(ws + 66 * MB);
  float*    ki      = (float*)(ws + 68 * MB);
  float*    wI      = (float*)(ws + 68 * MB + 512 * 1024);

  const dim3 blk(256);
  const dim3 tgrid(D_DIM / 32, D_DIM / 32);

  cast_bf16<<<dim3((D_DIM * T_DIM) / 1024), blk, 0, stream>>>(x, x_bf);
  cast_transpose<<<tgrid, blk, 0, stream>>>(Wq, Wcat_t, D_DIM, D_DIM);
  cast_transpose<<<tgrid, blk, 0, stream>>>(Wk, Wcat_t + (size_t)D_DIM * D_DIM, D_DIM, D_DIM);
  cast_transpose<<<tgrid, blk, 0, stream>>>(Wv, Wcat_t + (size_t)2 * D_DIM * D_DIM, D_DIM, D_DIM);
  cast_transpose<<<tgrid, blk, 0, stream>>>(Wo, Wo_t, D_DIM, D_DIM);

  // indexer path (fp32)
  idx_proj<<<dim3(6, T_DIM / 64), blk, 0, stream>>>(x, Wq_idx, Wk_idx, Ww_idx, qi, ki, wI);
  idx_scores_rt<<<dim3(T_DIM / 64, T_DIM / 64), blk, 0, stream>>>(qi, ki, wI, scores);
  select_mask<<<dim3(T_DIM), blk, 0, stream>>>(scores, maskbits);

  // fused qkv projection: [2048][6144] = x_bf @ Wcat_t^T (overwrites scores)
  gemm_bt<1><<<dim3(3 * D_DIM / 128, T_DIM / 128), blk, 0, stream>>>(
      x_bf, Wcat_t, qkv_bf, T_DIM, 3 * D_DIM, D_DIM);

  // v^T (vt overwrites Wq_t -- dead)
  transpose_bf<<<dim3(D_DIM / 64, T_DIM / 64), blk, 0, stream>>>(
      qkv_bf + 2 * D_DIM, vt_bf, 3 * D_DIM);

  // head-major q/k copies (q_h overwrites Wv_t, k_h overwrites x_bf -- both dead)
  qk_head<<<dim3(H_N, T_DIM / 128), blk, 0, stream>>>(qkv_bf, q_h, k_h);

  // flash masked attention (h = fast grid dim for XCD-shared K/V tiles)
  flash_attn4<<<dim3(H_N, T_DIM / 128), blk, 0, stream>>>(
      q_h, k_h, vt_bf, maskbits, attn_bf);

  // output projection -> f32
  gemm_bt<0><<<dim3(D_DIM / 128, T_DIM / 128), blk, 0, stream>>>(
      attn_bf, Wo_t, out, T_DIM, D_DIM, D_DIM);
}